// Round 1
// 252.653 us; speedup vs baseline: 1.1310x; 1.1310x over previous
//
#include <hip/hip_runtime.h>

// ---------------------------------------------------------------------------
// CESLayer: out[b,o] = cos(x@angle^T + bias) * exp(x@log|w|^T)
// B=262144, I=O=128. Memory floor ~38-42us.
// R4: fix the VGPR-spill stall found in R3's counters (VGPR=116 < the 128
// weight regs the design needed -> per-tile weight refetch from L2 serialized
// the MFMAs; MfmaUtil 16%, VALUBusy 30%, both pipes starved).
//   - 512-thread blocks, 8 waves; wave w owns 16 O-cols -> weights are only
//     64 VGPR/wave and ACTUALLY stay resident under __launch_bounds__(512,4).
//   - x tile (16x128 fp32) staged cooperatively ONCE per block: each thread
//     loads one float4, does the fp32->bf16 hi/lo split (cvt work /8 vs R3's
//     per-wave redundant convert), writes to double-buffered LDS.
//   - LDS XOR-swizzle (byte ^= (row&7)<<4) on both write and read: row stride
//     is 256B, so un-swizzled ds_read_b128 A-fragments would be a 16-way
//     bank conflict.
//   - depth-1 float4 prefetch issued BEFORE the barrier; epilogue stores
//     issued AFTER it, so the pf wait is vmcnt(4) (stores newer), not a drain.
// ---------------------------------------------------------------------------

typedef __attribute__((ext_vector_type(8))) short bf16x8;   // 8 bf16 = 4 VGPRs
typedef __attribute__((ext_vector_type(4))) float f32x4;

#define MFMA(a, b, c) __builtin_amdgcn_mfma_f32_16x16x32_bf16((a), (b), (c), 0, 0, 0)

__device__ __forceinline__ unsigned short f2bf_rne(float f) {
    unsigned u = __float_as_uint(f);
    unsigned r = u + 0x7FFFu + ((u >> 16) & 1u);
    return (unsigned short)(r >> 16);
}

// Split fp32 -> bf16 hi (truncated) + bf16 lo (RNE of exact residual).
__device__ __forceinline__ void bf16_split(float f, unsigned short& hi, unsigned short& lo) {
    unsigned uh = __float_as_uint(f) & 0xFFFF0000u;
    hi = (unsigned short)(uh >> 16);
    lo = f2bf_rne(f - __uint_as_float(uh));
}

// Pack two floats into one dword of bf16-hi (low=f0) and one of bf16-lo.
__device__ __forceinline__ void cvt_pair(float f0, float f1, unsigned& h, unsigned& l) {
    unsigned u0 = __float_as_uint(f0), u1 = __float_as_uint(f1);
    unsigned uh0 = u0 & 0xFFFF0000u, uh1 = u1 & 0xFFFF0000u;
    h = (uh0 >> 16) | uh1;
    float r0 = f0 - __uint_as_float(uh0);
    float r1 = f1 - __uint_as_float(uh1);
    unsigned v0 = __float_as_uint(r0), v1 = __float_as_uint(r1);
    v0 = v0 + 0x7FFFu + ((v0 >> 16) & 1u);
    v1 = v1 + 0x7FFFu + ((v1 >> 16) & 1u);
    l = (v0 >> 16) | (v1 & 0xFFFF0000u);
}

// ---------------------------------------------------------------------------
// Prep: angle=atan2(wi,wr), logmag=0.5*log(wr^2+wi^2), bf16 hi/lo split.
// ws layout (ushort): [0:16K) ang_hi [16K:32K) ang_lo [32K:48K) lg_hi [48K:64K) lg_lo
// ---------------------------------------------------------------------------
__global__ void ces_prep(const float* __restrict__ wr, const float* __restrict__ wi,
                         unsigned short* __restrict__ wsplit) {
    int idx = blockIdx.x * 256 + threadIdx.x;   // 0..16383
    float a = wr[idx], b = wi[idx];
    float r2 = a * a + b * b;
    float ang = atan2f(b, a);
    float lg = 0.5f * logf(r2);
    unsigned short ah, al, gh, gl;
    bf16_split(ang, ah, al);
    bf16_split(lg, gh, gl);
    wsplit[idx]         = ah;
    wsplit[16384 + idx] = al;
    wsplit[32768 + idx] = gh;
    wsplit[49152 + idx] = gl;
}

// ---------------------------------------------------------------------------
// Main. 512 threads = 8 waves; wave w owns O-cols [16w, 16w+16).
// MFMA 16x16x32 bf16 layouts (verified R1/R2): A: m=lane&15, k=quad*8+j;
// B: n=lane&15, k=quad*8+j; C/D: col=lane&15, row=quad*4+reg.
// LDS per buffer: hi[16][128] bf16 at +0 (4KB), lo at +4096. Buf1 at +8192.
// ---------------------------------------------------------------------------
#define NT 16   // 16-row tiles per block; grid 1024 -> 16384 tiles total

__global__ __launch_bounds__(512, 4) void ces_main(
        const float* __restrict__ x,
        const unsigned short* __restrict__ wsplit,
        const float* __restrict__ bias,
        float* __restrict__ out) {
    __shared__ __align__(16) unsigned short smem[8192];   // 16 KiB, 2 buffers
    char* smemb = (char*)smem;

    const int tid  = threadIdx.x;
    const int wave = tid >> 6;
    const int lane = tid & 63;
    const int quad = lane >> 4;
    const int l16  = lane & 15;
    const int n0   = wave * 16;

    // ---- weight fragments into registers (once per block): 64 regs/wave ----
    bf16x8 wa_h[4], wa_l[4], wg_h[4], wg_l[4];
    {
        const int o = n0 + l16;
#pragma unroll
        for (int ks = 0; ks < 4; ++ks) {
            const int off = o * 128 + ks * 32 + quad * 8;
            wa_h[ks] = *(const bf16x8*)(wsplit + off);
            wa_l[ks] = *(const bf16x8*)(wsplit + 16384 + off);
            wg_h[ks] = *(const bf16x8*)(wsplit + 32768 + off);
            wg_l[ks] = *(const bf16x8*)(wsplit + 49152 + off);
        }
    }
    const float bias_v = bias[n0 + l16];

    // ---- LDS byte addresses, XOR-swizzled by row to break bank conflicts ----
    // write: thread t owns row t>>5, 4 cols starting at (t&31)*4 (8B hi + 8B lo)
    const int wrow = tid >> 5;
    const int wb = (wrow * 256 + (tid & 31) * 8) ^ ((wrow & 7) << 4);
    // read: A-frag lane l: row=l16, k-bytes ks*64 + quad*16, 16B
    int rb[4];
#pragma unroll
    for (int ks = 0; ks < 4; ++ks)
        rb[ks] = (l16 * 256 + ks * 64 + quad * 16) ^ ((l16 & 7) << 4);

    const float* xb = x + (size_t)blockIdx.x * (NT * 2048) + tid * 4;

    // ---- prologue: stage tile 0 into buf0, prefetch tile 1 ----
    {
        float4 v = *(const float4*)xb;
        unsigned h0, l0, h1, l1;
        cvt_pair(v.x, v.y, h0, l0);
        cvt_pair(v.z, v.w, h1, l1);
        *(uint2*)(smemb + wb)        = make_uint2(h0, h1);
        *(uint2*)(smemb + wb + 4096) = make_uint2(l0, l1);
    }
    float4 pf = *(const float4*)(xb + 2048);
    __syncthreads();

    for (int i = 0; i < NT; ++i) {
        const int bo = (i & 1) << 13;

        // ---- MFMA: K=128 in 4 steps, 6 MFMAs each (3-term hi/lo x 2 GEMMs) ----
        f32x4 accY = {0.f, 0.f, 0.f, 0.f};
        f32x4 accG = {0.f, 0.f, 0.f, 0.f};
#pragma unroll
        for (int ks = 0; ks < 4; ++ks) {
            bf16x8 a_h = *(const bf16x8*)(smemb + (bo + rb[ks]));
            bf16x8 a_l = *(const bf16x8*)(smemb + (bo + rb[ks] + 4096));
            accY = MFMA(a_h, wa_h[ks], accY);
            accG = MFMA(a_h, wg_h[ks], accG);
            accY = MFMA(a_h, wa_l[ks], accY);
            accG = MFMA(a_h, wg_l[ks], accG);
            accY = MFMA(a_l, wa_h[ks], accY);
            accG = MFMA(a_l, wg_h[ks], accG);
        }

        // ---- stage tile i+1 (held in pf) into the other buffer ----
        {
            const int nbo = bo ^ 8192;
            unsigned h0, l0, h1, l1;
            cvt_pair(pf.x, pf.y, h0, l0);
            cvt_pair(pf.z, pf.w, h1, l1);
            *(uint2*)(smemb + (nbo + wb))        = make_uint2(h0, h1);
            *(uint2*)(smemb + (nbo + wb + 4096)) = make_uint2(l0, l1);
        }
        // ---- prefetch tile i+2 (clamped: last 2 iters redundantly reload) ----
        {
            int tn = i + 2;
            if (tn > NT - 1) tn = NT - 1;
            pf = *(const float4*)(xb + tn * 2048);
        }
        __syncthreads();

        // ---- epilogue tile i: stores after barrier overlap next iter's work ----
        {
            float* op = out + ((size_t)(blockIdx.x * NT + i) * 16 + quad * 4) * 128 + n0 + l16;
#pragma unroll
            for (int r = 0; r < 4; ++r) {
                float y = accY[r] + bias_v;
                op[(size_t)r * 128] = __cosf(y) * __expf(accG[r]);
            }
        }
    }
}

extern "C" void kernel_launch(void* const* d_in, const int* in_sizes, int n_in,
                              void* d_out, int out_size, void* d_ws, size_t ws_size,
                              hipStream_t stream) {
    const float* x    = (const float*)d_in[0];
    const float* wr   = (const float*)d_in[1];
    const float* wi   = (const float*)d_in[2];
    const float* bias = (const float*)d_in[3];
    float* out = (float*)d_out;
    unsigned short* wsplit = (unsigned short*)d_ws;   // 128 KiB

    ces_prep<<<64, 256, 0, stream>>>(wr, wi, wsplit);

    ces_main<<<1024, 512, 0, stream>>>(x, wsplit, bias, out);
}